// Round 1
// 598.585 us; speedup vs baseline: 1.3958x; 1.3958x over previous
//
#include <hip/hip_runtime.h>

#define ALPHA 0.2f

// Cross-block state in module-owned device globals (d_ws avoided).
// No atomics anywhere: every buffer is fully overwritten each launch
// before it is read, so no zero-init kernel is needed.
__device__ float g_part[8192 * 576];   // per-block partials: E[64] | S[v][ch] (8*64)
__device__ float g_red[2 * 32 * 1024]; // stage-1 tree: [l|S][bc 32][i 1024]
__device__ float g_ctx[1024];          // ctx[n][ch][v]  (n*512 + ch*8 + v)

// =====================================================================
// Phase 1: per-(n,h,w) tile of 64 tokens (channel c) x 64 d.
// Fused K|V GEMM (WL = [d][128], K cols 0..63, V cols 64..127),
// thread tile 4 tok x 8 ch -> 32 FMA per 3 LDS b128 reads.
// affine+LReLU; K side exp-clamped. Per-channel sums E, S[v] written
// as per-block partials to g_part (plain coalesced stores, no atomics).
// LDS 48KB -> 3 blocks/CU (was 66KB -> 2).
// =====================================================================
__global__ __launch_bounds__(256) void k_kv(
    const float* __restrict__ x,
    const float* __restrict__ Wk, const float* __restrict__ sk, const float* __restrict__ bk,
    const float* __restrict__ Wv, const float* __restrict__ sv, const float* __restrict__ bv)
{
  __shared__ __align__(16) float sh[12288];   // 48KB: xt[64][64] | WL[64][128]
  float* xt = sh;          // [d][ci]
  float* WL = sh + 4096;   // [d][e], e<64 = K, e>=64 = V

  const int tid = threadIdx.x;
  const int bid = blockIdx.x;
  const int n  = bid >> 12;
  const int hw = bid & 4095;

  const float* xrow = x + (size_t)n * 16777216u + (size_t)hw * 64u;

  // stage x tile (d-major, ci contiguous): 4096 floats
  #pragma unroll
  for (int i = 0; i < 4; ++i) {
    int idx = tid + i * 256;              // 0..1023
    int d = idx >> 4, c4 = (idx & 15) * 4;
    *(float4*)&xt[d * 64 + c4] = *(const float4*)(xrow + (size_t)d * 262144u + c4);
  }
  // stage WL = [Wk | Wv]: 8192 floats
  #pragma unroll
  for (int i = 0; i < 8; ++i) {
    int idx = tid + i * 256;              // float4 id 0..2047
    int d = idx >> 5, e4 = (idx & 31) * 4;
    const float* src = (e4 < 64) ? (Wk + d * 64 + e4) : (Wv + d * 64 + e4 - 64);
    *(float4*)&WL[d * 128 + e4] = *(const float4*)src;
  }
  __syncthreads();

  const int tok0 = (tid & 15) * 4;    // 4 tokens per thread
  const int eg   = tid >> 4;          // 0..15 channel-group (0..7 K, 8..15 V)
  const int e0   = eg * 8;

  float acc[4][8];
  #pragma unroll
  for (int t = 0; t < 4; ++t)
    #pragma unroll
    for (int j = 0; j < 8; ++j) acc[t][j] = 0.f;

  #pragma unroll 4
  for (int d = 0; d < 64; ++d) {
    float4 xv = *(const float4*)&xt[d * 64 + tok0];
    float4 wa = *(const float4*)&WL[d * 128 + e0];
    float4 wb = *(const float4*)&WL[d * 128 + e0 + 4];
    float xr[4] = {xv.x, xv.y, xv.z, xv.w};
    float w[8]  = {wa.x, wa.y, wa.z, wa.w, wb.x, wb.y, wb.z, wb.w};
    #pragma unroll
    for (int t = 0; t < 4; ++t)
      #pragma unroll
      for (int j = 0; j < 8; ++j) acc[t][j] += xr[t] * w[j];
  }

  const bool isK = (eg < 8);
  const int  ec  = isK ? e0 : (e0 - 64);
  const float* sp = (isK ? sk : sv) + ec;
  const float* bp = (isK ? bk : bv) + ec;
  float s8[8], b8[8];
  *(float4*)&s8[0] = *(const float4*)(sp);
  *(float4*)&s8[4] = *(const float4*)(sp + 4);
  *(float4*)&b8[0] = *(const float4*)(bp);
  *(float4*)&b8[4] = *(const float4*)(bp + 4);

  __syncthreads();   // all GEMM reads of sh done; overlay eK/vV on xt/WL

  float* eK = sh;            // [tok][65]
  float* vV = sh + 4160;     // [tok][65]
  float* dst = (isK ? eK : vV) + ec;
  #pragma unroll
  for (int t = 0; t < 4; ++t) {
    #pragma unroll
    for (int j = 0; j < 8; ++j) {
      float y = acc[t][j] * s8[j] + b8[j];
      y = (y >= 0.f) ? y : ALPHA * y;
      if (isK) y = __expf(fminf(y, 60.f));
      dst[(tok0 + t) * 65 + j] = y;
    }
  }
  __syncthreads();

  {
    float* pE = sh + 8320;          // [4][64]   (scratch above eK/vV)
    float* pS = sh + 8320 + 256;    // [4][64][8]
    const int ch = tid & 63;
    const int tq = tid >> 6;
    const int a8 = ch & ~7;

    float E = 0.f;
    float S[8];
    #pragma unroll
    for (int v = 0; v < 8; ++v) S[v] = 0.f;
    for (int t = tq * 16; t < tq * 16 + 16; ++t) {
      float e = eK[t * 65 + ch];
      E += e;
      #pragma unroll
      for (int v = 0; v < 8; ++v) S[v] += e * vV[t * 65 + a8 + v];
    }
    pE[tq * 64 + ch] = E;
    #pragma unroll
    for (int v = 0; v < 8; ++v) pS[(tq * 64 + ch) * 8 + v] = S[v];
    __syncthreads();

    if (tid < 64) {
      float* gp = g_part + (size_t)bid * 576u;
      float E4 = pE[tid] + pE[64 + tid] + pE[128 + tid] + pE[192 + tid];
      gp[tid] = E4;                               // coalesced 256B row
      #pragma unroll
      for (int v = 0; v < 8; ++v) {
        float S4 = pS[tid * 8 + v] + pS[(64 + tid) * 8 + v]
                 + pS[(128 + tid) * 8 + v] + pS[(192 + tid) * 8 + v];
        gp[64 + v * 64 + tid] = S4;               // coalesced 256B rows
      }
    }
  }
}

// =====================================================================
// Phase 1.25: stage-1 tree reduce of per-block partials.
// 128 blocks = 32 b-chunks (128 blocks each) x 4 output-chunks (256 out).
// =====================================================================
__global__ __launch_bounds__(256) void k_red() {
  const int ob = blockIdx.x & 3;
  const int bc = blockIdx.x >> 2;                 // 0..31
  const int i  = ob * 256 + threadIdx.x;          // i = n*512 + ch*8 + v
  const int n = i >> 9, ch = (i & 511) >> 3, v = i & 7;
  const float* base = g_part + ((size_t)n * 4096u + (size_t)bc * 128u) * 576u;
  float l = 0.f, S = 0.f;
  #pragma unroll 8
  for (int b = 0; b < 128; ++b) {
    l += base[(size_t)b * 576u + ch];
    S += base[(size_t)b * 576u + 64u + (size_t)v * 64u + ch];
  }
  g_red[bc * 1024 + i]         = l;
  g_red[32768 + bc * 1024 + i] = S;
}

// =====================================================================
// Phase 1.5: final reduce -> guarded ctx (NaN structurally impossible).
// =====================================================================
__global__ __launch_bounds__(256) void k_ctx() {
  int i = blockIdx.x * 256 + threadIdx.x;   // i = n*512 + ch*8 + v
  if (i >= 1024) return;
  float l = 0.f, S = 0.f;
  #pragma unroll
  for (int r = 0; r < 32; ++r) {
    l += g_red[r * 1024 + i];
    S += g_red[32768 + r * 1024 + i];
  }
  float c = (l > 0.f) ? (S / l) : 0.f;
  if (!(__builtin_fabsf(c) < 1e30f)) c = 0.f;   // catches NaN/inf too
  g_ctx[i] = c;
}

// =====================================================================
// Phase 2: block = (n, h', w'). Q tokens: c_t=(c'&7)*8+(h'>>3),
// h_t=(h'&7)*8+(w'>>3) fixed, w_t=(w'&7)*8+v''. Recompute Q, agg,
// rep GEMM + affine + LReLU, residual add. WrL overlays xql (staged
// after Q-GEMM) to keep LDS ~68 KB -> 2 blocks/CU.  [unchanged]
// =====================================================================
__global__ __launch_bounds__(256) void k_att(
    const float* __restrict__ x,
    const float* __restrict__ Wq, const float* __restrict__ sq, const float* __restrict__ bq,
    const float* __restrict__ Wr, const float* __restrict__ sr, const float* __restrict__ br,
    float* __restrict__ out)
{
  __shared__ __align__(16) float WqL[64 * 64];   // [d][ch]
  __shared__ __align__(16) float xw[64 * 64];    // xql [d][tok], then WrL [e][d]
  __shared__ float qL[64 * 65];                  // [tok][ch]
  __shared__ float aggL[64 * 65];                // [c'][e]
  __shared__ float ctxL[64 * 9];                 // [a*8+k][v]
  __shared__ float srL[64], brL[64];

  const int tid = threadIdx.x;
  const int bid = blockIdx.x;
  const int n  = bid >> 12;
  const int hwp = bid & 4095;
  const int hp = hwp >> 6, wp = hwp & 63;

  const int jc    = hp >> 3;
  const int h_t   = (hp & 7) * 8 + (wp >> 3);
  const int wbase = (wp & 7) * 8;

  #pragma unroll
  for (int i = 0; i < 4; ++i) {
    int idx = tid + i * 256;
    int r = idx >> 4, c4 = (idx & 15) * 4;
    *(float4*)&WqL[r * 64 + c4] = *(const float4*)(Wq + r * 64 + c4);
  }
  if (tid < 64) { srL[tid] = sr[tid]; brL[tid] = br[tid]; }

  for (int i = tid; i < 512; i += 256) {
    int ch = i >> 3, v = i & 7;
    ctxL[ch * 9 + v] = g_ctx[n * 512 + ch * 8 + v];
  }

  // gather x for the 64 needed tokens: xw[d][tok], tok = v''*8 + c'low
  {
    const size_t xb = (size_t)n * 16777216u + (size_t)h_t * 4096u;
    #pragma unroll
    for (int i = 0; i < 16; ++i) {
      int idx = tid + i * 256;
      int d = idx >> 6, tok = idx & 63;
      int vpp = tok >> 3, cl = tok & 7;
      xw[d * 64 + tok] = x[xb + (size_t)d * 262144u + (size_t)(wbase + vpp) * 64u + (cl * 8 + jc)];
    }
  }
  __syncthreads();

  // Q GEMM (2 tok x 8 ch per thread) + affine + LReLU + softmax over head
  {
    const int tok0 = (tid & 31) * 2;
    const int ch0  = (tid >> 5) * 8;
    float acc0[8], acc1[8];
    #pragma unroll
    for (int j = 0; j < 8; ++j) { acc0[j] = 0.f; acc1[j] = 0.f; }
    #pragma unroll 4
    for (int d = 0; d < 64; ++d) {
      float2 xv = *(const float2*)&xw[d * 64 + tok0];
      float4 wa = *(const float4*)&WqL[d * 64 + ch0];
      float4 wb = *(const float4*)&WqL[d * 64 + ch0 + 4];
      float w[8] = {wa.x, wa.y, wa.z, wa.w, wb.x, wb.y, wb.z, wb.w};
      #pragma unroll
      for (int j = 0; j < 8; ++j) { acc0[j] += xv.x * w[j]; acc1[j] += xv.y * w[j]; }
    }
    float sv8[8], bv8[8];
    *(float4*)&sv8[0] = *(const float4*)(sq + ch0);
    *(float4*)&sv8[4] = *(const float4*)(sq + ch0 + 4);
    *(float4*)&bv8[0] = *(const float4*)(bq + ch0);
    *(float4*)&bv8[4] = *(const float4*)(bq + ch0 + 4);
    #pragma unroll
    for (int i = 0; i < 2; ++i) {
      float* a = (i == 0) ? acc0 : acc1;
      float mx = -3.0e38f;
      #pragma unroll
      for (int j = 0; j < 8; ++j) {
        float y = a[j] * sv8[j] + bv8[j];
        y = (y >= 0.f) ? y : ALPHA * y;
        a[j] = y;
        mx = fmaxf(mx, y);
      }
      float sum = 0.f;
      #pragma unroll
      for (int j = 0; j < 8; ++j) { a[j] = __expf(a[j] - mx); sum += a[j]; }
      float inv = 1.f / sum;
      #pragma unroll
      for (int j = 0; j < 8; ++j) qL[(tok0 + i) * 65 + ch0 + j] = a[j] * inv;
    }
  }
  __syncthreads();   // Q-GEMM done with xw -> repurpose as WrL

  #pragma unroll
  for (int i = 0; i < 4; ++i) {
    int idx = tid + i * 256;
    int r = idx >> 4, c4 = (idx & 15) * 4;
    *(float4*)&xw[r * 64 + c4] = *(const float4*)(Wr + r * 64 + c4);
  }

  // agg[c'][e]
  {
    const int cp = tid & 63, eb = tid >> 6;
    const int kk = cp >> 3, cl = cp & 7;
    #pragma unroll
    for (int je = 0; je < 16; ++je) {
      int e = eb * 16 + je;
      int a = e >> 3, vpp = e & 7;
      const float* cx = &ctxL[(a * 8 + kk) * 9];
      const float* qr = &qL[(vpp * 8 + cl) * 65 + a * 8];
      float s = 0.f;
      #pragma unroll
      for (int v = 0; v < 8; ++v) s += cx[v] * qr[v];
      aggL[cp * 65 + e] = s;
    }
  }
  __syncthreads();

  // rep GEMM + residual (lanes = c', coalesced 256B rows)
  {
    const int ci = tid & 63, dq = tid >> 6;
    float accr[16];
    #pragma unroll
    for (int i = 0; i < 16; ++i) accr[i] = 0.f;
    #pragma unroll 4
    for (int e = 0; e < 64; ++e) {
      float av = aggL[ci * 65 + e];
      const float* wr = &xw[e * 64 + dq * 16];
      #pragma unroll
      for (int i = 0; i < 16; ++i) accr[i] += av * wr[i];
    }
    const size_t xb = (size_t)n * 16777216u + (size_t)hwp * 64u + (size_t)ci;
    #pragma unroll
    for (int i = 0; i < 16; ++i) {
      int di = dq * 16 + i;
      float y = accr[i] * srL[di] + brL[di];
      y = (y >= 0.f) ? y : ALPHA * y;
      out[xb + (size_t)di * 262144u] = x[xb + (size_t)di * 262144u] + y;
    }
  }
}

// =====================================================================
extern "C" void kernel_launch(void* const* d_in, const int* in_sizes, int n_in,
                              void* d_out, int out_size, void* d_ws, size_t ws_size,
                              hipStream_t stream)
{
  (void)in_sizes; (void)n_in; (void)out_size; (void)d_ws; (void)ws_size;

  const float* x  = (const float*)d_in[0];
  const float* Wk = (const float*)d_in[1];
  const float* sk = (const float*)d_in[2];
  const float* bk = (const float*)d_in[3];
  const float* Wq = (const float*)d_in[4];
  const float* sq = (const float*)d_in[5];
  const float* bq = (const float*)d_in[6];
  const float* Wv = (const float*)d_in[7];
  const float* sv = (const float*)d_in[8];
  const float* bv = (const float*)d_in[9];
  const float* Wr = (const float*)d_in[10];
  const float* sr = (const float*)d_in[11];
  const float* br = (const float*)d_in[12];
  float* out = (float*)d_out;

  k_kv  <<<dim3(8192), dim3(256), 0, stream>>>(x, Wk, sk, bk, Wv, sv, bv);
  k_red <<<dim3(128),  dim3(256), 0, stream>>>();
  k_ctx <<<dim3(4),    dim3(256), 0, stream>>>();
  k_att <<<dim3(8192), dim3(256), 0, stream>>>(x, Wq, sq, bq, Wr, sr, br, out);
}

// Round 2
// 496.251 us; speedup vs baseline: 1.6836x; 1.2062x over previous
//
#include <hip/hip_runtime.h>

#define ALPHA 0.2f

typedef const __attribute__((address_space(1))) unsigned int gu32;
typedef __attribute__((address_space(3))) unsigned int lu32;

// Cross-block state in module-owned device globals (d_ws avoided).
// No atomics anywhere: every buffer is fully overwritten each launch
// before it is read, so no zero-init kernel is needed.
__device__ float g_part[8192 * 576];   // per-block partials: E[64] | S[v][ch] (8*64)
__device__ float g_red[2 * 32 * 1024]; // stage-1 tree: [l|S][bc 32][i 1024]
__device__ float g_ctx[1024];          // ctx[n][ch][v]  (n*512 + ch*8 + v)

// =====================================================================
// Phase 1: per-(n,h,w) tile of 64 tokens (channel c) x 64 d.
// Fused K|V GEMM (WL = [d][128]), thread tile 4 tok x 8 ch.
// Staging via global_load_lds width-16 (dest is linear base+lane*16).
// eK/vV stored stride-68 -> float4 reduce reads (conflict-free) and
// float4 epilogue writes (at the b128 bank floor).
// =====================================================================
__global__ __launch_bounds__(256) void k_kv(
    const float* __restrict__ x,
    const float* __restrict__ Wk, const float* __restrict__ sk, const float* __restrict__ bk,
    const float* __restrict__ Wv, const float* __restrict__ sv, const float* __restrict__ bv)
{
  __shared__ __align__(16) float sh[12288];   // 48KB: xt[64][64] | WL[64][128]
  float* xt = sh;          // [d][ci] 4096
  float* WL = sh + 4096;   // [d][e]  8192, e<64 = K, e>=64 = V

  const int tid = threadIdx.x;
  const int bid = blockIdx.x;
  const int n  = bid >> 12;
  const int hw = bid & 4095;

  const float* xrow = x + (size_t)n * 16777216u + (size_t)hw * 64u;

  // stage x tile: dest byte offset = idx*16 -> linear per wave
  #pragma unroll
  for (int i = 0; i < 4; ++i) {
    int idx = tid + i * 256;              // 0..1023
    int d = idx >> 4, c4 = (idx & 15) * 4;
    __builtin_amdgcn_global_load_lds((gu32*)(xrow + (size_t)d * 262144u + c4),
                                     (lu32*)&xt[idx * 4], 16, 0, 0);
  }
  // stage WL = [Wk | Wv]: dest byte offset = idx*16 -> linear per wave
  #pragma unroll
  for (int i = 0; i < 8; ++i) {
    int idx = tid + i * 256;              // 0..2047
    int d = idx >> 5, e4 = (idx & 31) * 4;
    const float* src = (e4 < 64) ? (Wk + d * 64 + e4) : (Wv + d * 64 + e4 - 64);
    __builtin_amdgcn_global_load_lds((gu32*)src, (lu32*)&WL[idx * 4], 16, 0, 0);
  }

  const int tok0 = (tid & 15) * 4;    // 4 tokens per thread
  const int eg   = tid >> 4;          // 0..15 channel-group (0..7 K, 8..15 V)
  const int e0   = eg * 8;
  const bool isK = (eg < 8);
  const int  ec  = isK ? e0 : (e0 - 64);

  // issue affine params early (independent of LDS)
  const float* sp = (isK ? sk : sv) + ec;
  const float* bp = (isK ? bk : bv) + ec;
  float s8[8], b8[8];
  *(float4*)&s8[0] = *(const float4*)(sp);
  *(float4*)&s8[4] = *(const float4*)(sp + 4);
  *(float4*)&b8[0] = *(const float4*)(bp);
  *(float4*)&b8[4] = *(const float4*)(bp + 4);

  __syncthreads();   // barrier drains vmcnt -> staging complete

  float acc[4][8];
  #pragma unroll
  for (int t = 0; t < 4; ++t)
    #pragma unroll
    for (int j = 0; j < 8; ++j) acc[t][j] = 0.f;

  #pragma unroll 4
  for (int d = 0; d < 64; ++d) {
    float4 xv = *(const float4*)&xt[d * 64 + tok0];
    float4 wa = *(const float4*)&WL[d * 128 + e0];
    float4 wb = *(const float4*)&WL[d * 128 + e0 + 4];
    float xr[4] = {xv.x, xv.y, xv.z, xv.w};
    float w[8]  = {wa.x, wa.y, wa.z, wa.w, wb.x, wb.y, wb.z, wb.w};
    #pragma unroll
    for (int t = 0; t < 4; ++t)
      #pragma unroll
      for (int j = 0; j < 8; ++j) acc[t][j] += xr[t] * w[j];
  }

  __syncthreads();   // all GEMM reads of sh done; overlay eK/vV

  float* eK = sh;            // [tok][68]
  float* vV = sh + 4352;     // [tok][68]
  float* dst = (isK ? eK : vV);
  #pragma unroll
  for (int t = 0; t < 4; ++t) {
    float y8[8];
    #pragma unroll
    for (int j = 0; j < 8; ++j) {
      float y = acc[t][j] * s8[j] + b8[j];
      y = (y >= 0.f) ? y : ALPHA * y;
      if (isK) y = __expf(fminf(y, 60.f));
      y8[j] = y;
    }
    *(float4*)&dst[(tok0 + t) * 68 + ec]     = *(float4*)&y8[0];
    *(float4*)&dst[(tok0 + t) * 68 + ec + 4] = *(float4*)&y8[4];
  }
  __syncthreads();

  {
    float* pE = sh + 8704;          // [4][64]
    float* pS = sh + 8960;          // [4][64][8]
    const int ch = tid & 63;
    const int tq = tid >> 6;
    const int a8 = ch & ~7;

    float E = 0.f;
    float S[8];
    #pragma unroll
    for (int v = 0; v < 8; ++v) S[v] = 0.f;
    for (int t = tq * 16; t < tq * 16 + 16; ++t) {
      float e = eK[t * 68 + ch];
      float4 v0 = *(const float4*)&vV[t * 68 + a8];
      float4 v1 = *(const float4*)&vV[t * 68 + a8 + 4];
      E += e;
      S[0] += e * v0.x; S[1] += e * v0.y; S[2] += e * v0.z; S[3] += e * v0.w;
      S[4] += e * v1.x; S[5] += e * v1.y; S[6] += e * v1.z; S[7] += e * v1.w;
    }
    pE[tq * 64 + ch] = E;
    #pragma unroll
    for (int v = 0; v < 8; ++v) pS[(tq * 64 + ch) * 8 + v] = S[v];
    __syncthreads();

    if (tid < 64) {
      float* gp = g_part + (size_t)bid * 576u;
      float E4 = pE[tid] + pE[64 + tid] + pE[128 + tid] + pE[192 + tid];
      gp[tid] = E4;                               // coalesced 256B row
      #pragma unroll
      for (int v = 0; v < 8; ++v) {
        float S4 = pS[tid * 8 + v] + pS[(64 + tid) * 8 + v]
                 + pS[(128 + tid) * 8 + v] + pS[(192 + tid) * 8 + v];
        gp[64 + v * 64 + tid] = S4;               // coalesced 256B rows
      }
    }
  }
}

// =====================================================================
// Phase 1.25: stage-1 tree reduce of per-block partials.
// =====================================================================
__global__ __launch_bounds__(256) void k_red() {
  const int ob = blockIdx.x & 3;
  const int bc = blockIdx.x >> 2;                 // 0..31
  const int i  = ob * 256 + threadIdx.x;          // i = n*512 + ch*8 + v
  const int n = i >> 9, ch = (i & 511) >> 3, v = i & 7;
  const float* base = g_part + ((size_t)n * 4096u + (size_t)bc * 128u) * 576u;
  float l = 0.f, S = 0.f;
  #pragma unroll 8
  for (int b = 0; b < 128; ++b) {
    l += base[(size_t)b * 576u + ch];
    S += base[(size_t)b * 576u + 64u + (size_t)v * 64u + ch];
  }
  g_red[bc * 1024 + i]         = l;
  g_red[32768 + bc * 1024 + i] = S;
}

// =====================================================================
// Phase 1.5: final reduce -> guarded ctx (NaN structurally impossible).
// =====================================================================
__global__ __launch_bounds__(256) void k_ctx() {
  int i = blockIdx.x * 256 + threadIdx.x;   // i = n*512 + ch*8 + v
  if (i >= 1024) return;
  float l = 0.f, S = 0.f;
  #pragma unroll
  for (int r = 0; r < 32; ++r) {
    l += g_red[r * 1024 + i];
    S += g_red[32768 + r * 1024 + i];
  }
  float c = (l > 0.f) ? (S / l) : 0.f;
  if (!(__builtin_fabsf(c) < 1e30f)) c = 0.f;   // catches NaN/inf too
  g_ctx[i] = c;
}

// =====================================================================
// Phase 2: jc-swizzled blockIdx so the 8 blocks sharing x gather rows
// (same n, hp&7, wp; differing jc) are lin, lin+8, .. lin+56: same XCD,
// temporally adjacent -> each 64B line fetched once serves 8 blocks.
// aggL overlays WqL (dead after Q-GEMM): LDS 53KB -> 3 blocks/CU.
// qL rotation-swizzled (chunk rot 4*t mod 64) -> float4 agg reads.
// =====================================================================
__global__ __launch_bounds__(256) void k_att(
    const float* __restrict__ x,
    const float* __restrict__ Wq, const float* __restrict__ sq, const float* __restrict__ bq,
    const float* __restrict__ Wr, const float* __restrict__ sr, const float* __restrict__ br,
    float* __restrict__ out)
{
  __shared__ __align__(16) float WqA[64 * 65];   // WqL [d][ch] (stride 64) then aggL [c'][e] (stride 65)
  __shared__ __align__(16) float xw[64 * 64];    // xql [d][tok], then WrL [e][d]
  __shared__ __align__(16) float qL[64 * 64];    // [tok][rot-swizzled ch]
  __shared__ __align__(16) float ctxL[64 * 12];  // [a*8+k][v] stride 12
  __shared__ float srL[64], brL[64];

  const int tid = threadIdx.x;
  const int lin = blockIdx.x;

  // jc-swizzle decode (bijective: lin = rest<<6 | jc<<3 | xcd)
  const int xcd   = lin & 7;
  const int jc    = (lin >> 3) & 7;
  const int rest  = lin >> 6;              // 0..127
  const int combo = rest * 8 + xcd;        // 0..1023 -> (n, hp_lo, wp)
  const int n     = combo >> 9;
  const int hp_lo = (combo >> 6) & 7;
  const int wp    = combo & 63;
  const int hp    = jc * 8 + hp_lo;
  const int hwp   = hp * 64 + wp;

  const int h_t   = hp_lo * 8 + (wp >> 3);
  const int wbase = (wp & 7) * 8;

  // stage Wq: dest byte offset = idx*16 -> linear per wave
  #pragma unroll
  for (int i = 0; i < 4; ++i) {
    int idx = tid + i * 256;
    __builtin_amdgcn_global_load_lds((gu32*)(Wq + idx * 4),
                                     (lu32*)&WqA[idx * 4], 16, 0, 0);
  }
  if (tid < 64) { srL[tid] = sr[tid]; brL[tid] = br[tid]; }

  for (int i = tid; i < 512; i += 256) {
    int ch = i >> 3, v = i & 7;
    ctxL[ch * 12 + v] = g_ctx[n * 512 + ch * 8 + v];
  }

  // gather x for the 64 needed tokens: xw[d][tok], tok = v''*8 + c'low
  {
    const size_t xb = (size_t)n * 16777216u + (size_t)h_t * 4096u;
    #pragma unroll
    for (int i = 0; i < 16; ++i) {
      int idx = tid + i * 256;
      int d = idx >> 6, tok = idx & 63;
      int vpp = tok >> 3, cl = tok & 7;
      xw[d * 64 + tok] = x[xb + (size_t)d * 262144u + (size_t)(wbase + vpp) * 64u + (cl * 8 + jc)];
    }
  }
  __syncthreads();

  // Q GEMM (2 tok x 8 ch per thread) + affine + LReLU + softmax over head
  {
    const int tok0 = (tid & 31) * 2;
    const int ch0  = (tid >> 5) * 8;
    float acc0[8], acc1[8];
    #pragma unroll
    for (int j = 0; j < 8; ++j) { acc0[j] = 0.f; acc1[j] = 0.f; }
    #pragma unroll 4
    for (int d = 0; d < 64; ++d) {
      float2 xv = *(const float2*)&xw[d * 64 + tok0];
      float4 wa = *(const float4*)&WqA[d * 64 + ch0];
      float4 wb = *(const float4*)&WqA[d * 64 + ch0 + 4];
      float w[8] = {wa.x, wa.y, wa.z, wa.w, wb.x, wb.y, wb.z, wb.w};
      #pragma unroll
      for (int j = 0; j < 8; ++j) { acc0[j] += xv.x * w[j]; acc1[j] += xv.y * w[j]; }
    }
    float sv8[8], bv8[8];
    *(float4*)&sv8[0] = *(const float4*)(sq + ch0);
    *(float4*)&sv8[4] = *(const float4*)(sq + ch0 + 4);
    *(float4*)&bv8[0] = *(const float4*)(bq + ch0);
    *(float4*)&bv8[4] = *(const float4*)(bq + ch0 + 4);
    #pragma unroll
    for (int i = 0; i < 2; ++i) {
      float* a = (i == 0) ? acc0 : acc1;
      float mx = -3.0e38f;
      #pragma unroll
      for (int j = 0; j < 8; ++j) {
        float y = a[j] * sv8[j] + bv8[j];
        y = (y >= 0.f) ? y : ALPHA * y;
        a[j] = y;
        mx = fmaxf(mx, y);
      }
      float sum = 0.f;
      #pragma unroll
      for (int j = 0; j < 8; ++j) { a[j] = __expf(a[j] - mx); sum += a[j]; }
      float inv = 1.f / sum;
      float o8[8];
      #pragma unroll
      for (int j = 0; j < 8; ++j) o8[j] = a[j] * inv;
      const int t = tok0 + i;
      const int rot = (4 * t) & 63;
      *(float4*)&qL[t * 64 + ((ch0 + rot) & 63)]     = *(float4*)&o8[0];
      *(float4*)&qL[t * 64 + ((ch0 + 4 + rot) & 63)] = *(float4*)&o8[4];
    }
  }
  __syncthreads();   // Q-GEMM done with xw & WqA -> repurpose both

  // stage Wr into xw: dest byte offset = idx*16 -> linear per wave
  #pragma unroll
  for (int i = 0; i < 4; ++i) {
    int idx = tid + i * 256;
    __builtin_amdgcn_global_load_lds((gu32*)(Wr + idx * 4),
                                     (lu32*)&xw[idx * 4], 16, 0, 0);
  }

  // agg[c'][e] into aggL (= WqA region, stride 65), float4 reads
  {
    float* aggL = WqA;
    const int cp = tid & 63, eb = tid >> 6;
    const int kk = cp >> 3, cl = cp & 7;
    #pragma unroll
    for (int je = 0; je < 16; ++je) {
      int e = eb * 16 + je;
      int a = e >> 3, vpp = e & 7;
      float4 c0 = *(const float4*)&ctxL[(a * 8 + kk) * 12];
      float4 c1 = *(const float4*)&ctxL[(a * 8 + kk) * 12 + 4];
      int t = vpp * 8 + cl;
      int rot = (4 * t) & 63;
      float4 q0 = *(const float4*)&qL[t * 64 + ((a * 8 + rot) & 63)];
      float4 q1 = *(const float4*)&qL[t * 64 + ((a * 8 + 4 + rot) & 63)];
      float s = q0.x * c0.x + q0.y * c0.y + q0.z * c0.z + q0.w * c0.w
              + q1.x * c1.x + q1.y * c1.y + q1.z * c1.z + q1.w * c1.w;
      aggL[cp * 65 + e] = s;
    }
  }
  __syncthreads();   // drains Wr vmcnt too

  // rep GEMM + residual (lanes = c', coalesced 256B rows)
  {
    const float* aggL = WqA;
    const int ci = tid & 63, dq = tid >> 6;
    float accr[16];
    #pragma unroll
    for (int i = 0; i < 16; ++i) accr[i] = 0.f;
    #pragma unroll 4
    for (int e = 0; e < 64; ++e) {
      float av = aggL[ci * 65 + e];
      const float* wr = &xw[e * 64 + dq * 16];
      #pragma unroll
      for (int i = 0; i < 16; ++i) accr[i] += av * wr[i];
    }
    const size_t xb = (size_t)n * 16777216u + (size_t)hwp * 64u + (size_t)ci;
    #pragma unroll
    for (int i = 0; i < 16; ++i) {
      int di = dq * 16 + i;
      float y = accr[i] * srL[di] + brL[di];
      y = (y >= 0.f) ? y : ALPHA * y;
      out[xb + (size_t)di * 262144u] = x[xb + (size_t)di * 262144u] + y;
    }
  }
}

// =====================================================================
extern "C" void kernel_launch(void* const* d_in, const int* in_sizes, int n_in,
                              void* d_out, int out_size, void* d_ws, size_t ws_size,
                              hipStream_t stream)
{
  (void)in_sizes; (void)n_in; (void)out_size; (void)d_ws; (void)ws_size;

  const float* x  = (const float*)d_in[0];
  const float* Wk = (const float*)d_in[1];
  const float* sk = (const float*)d_in[2];
  const float* bk = (const float*)d_in[3];
  const float* Wq = (const float*)d_in[4];
  const float* sq = (const float*)d_in[5];
  const float* bq = (const float*)d_in[6];
  const float* Wv = (const float*)d_in[7];
  const float* sv = (const float*)d_in[8];
  const float* bv = (const float*)d_in[9];
  const float* Wr = (const float*)d_in[10];
  const float* sr = (const float*)d_in[11];
  const float* br = (const float*)d_in[12];
  float* out = (float*)d_out;

  k_kv  <<<dim3(8192), dim3(256), 0, stream>>>(x, Wk, sk, bk, Wv, sv, bv);
  k_red <<<dim3(128),  dim3(256), 0, stream>>>();
  k_ctx <<<dim3(4),    dim3(256), 0, stream>>>();
  k_att <<<dim3(8192), dim3(256), 0, stream>>>(x, Wq, sq, bq, Wr, sr, br, out);
}